// Round 4
// baseline (107.084 us; speedup 1.0000x reference)
//
#include <hip/hip_runtime.h>
#include <math.h>

#define N1 8192
#define N2 8192
#define NBATCH 2
#define KNN 16
#define QPW 4              // queries per wave
#define NCHUNK (N1 / 64)

// Pack p1 = xyz1 + flow1 as float4(x, y, z, |p1|^2), and f1 as float4(fx, fy, fz, 0).
__global__ __launch_bounds__(256) void pw3_prep_kernel(
    const float* __restrict__ xyz1,
    const float* __restrict__ flow1,
    float4* __restrict__ p1p,
    float4* __restrict__ f1p) {
  int i = blockIdx.x * blockDim.x + threadIdx.x;  // 0 .. B*N1-1
  if (i >= NBATCH * N1) return;
  int b = i >> 13;            // / N1
  int m = i & (N1 - 1);
  const float* x1 = xyz1 + b * 3 * N1;
  const float* f1 = flow1 + b * 3 * N1;
  float fx = f1[m], fy = f1[N1 + m], fz = f1[2 * N1 + m];
  float px = x1[m] + fx;
  float py = x1[N1 + m] + fy;
  float pz = x1[2 * N1 + m] + fz;
  float n1 = (px * px + py * py) + pz * pz;   // match reference (p1*p1).sum(-1)
  p1p[i] = make_float4(px, py, pz, n1);
  f1p[i] = make_float4(fx, fy, fz, 0.0f);
}

// DPP shift-up-by-1 within each 16-lane row (row_shr:1). Lanes 0/16/32/48
// receive `old` (we pass -INF so the "candidate < prev" test is false there).
__device__ __forceinline__ float dpp_up1_f(float x, float old_v) {
  int r = __builtin_amdgcn_update_dpp(
      __builtin_bit_cast(int, old_v), __builtin_bit_cast(int, x),
      0x111, 0xf, 0xf, false);
  return __builtin_bit_cast(float, r);
}
__device__ __forceinline__ int dpp_up1_i(int x) {
  return __builtin_amdgcn_update_dpp(0, x, 0x111, 0xf, 0xf, false);
}

// lane ^ J exchange: DPP quad_perm for J=1,2; ds_swizzle (xor mode) for J=4,8.
template <int J>
__device__ __forceinline__ int lanexor_i(int x) {
  if constexpr (J == 1)
    return __builtin_amdgcn_update_dpp(x, x, 0xB1, 0xf, 0xf, false);  // [1,0,3,2]
  else if constexpr (J == 2)
    return __builtin_amdgcn_update_dpp(x, x, 0x4E, 0xf, 0xf, false);  // [2,3,0,1]
  else
    return __builtin_amdgcn_ds_swizzle(x, (J << 10) | 0x1F);
}
template <int J>
__device__ __forceinline__ float lanexor_f(float x) {
  return __builtin_bit_cast(float, lanexor_i<J>(__builtin_bit_cast(int, x)));
}

// One wave handles QPW=4 queries. Each 16-lane subgroup owns one query's
// sorted top-16 (dist,idx), one entry per lane, ascending (sub 15 = kth).
__global__ __launch_bounds__(256) void pw3_knn_kernel(
    const float* __restrict__ xyz2,
    const float4* __restrict__ p1p,
    const float4* __restrict__ f1p,
    float* __restrict__ out) {
  int lane = threadIdx.x & 63;
  int sub = lane & 15;
  int mygroup = lane >> 4;
  int gwave = (int)((blockIdx.x * blockDim.x + threadIdx.x) >> 6);
  int q0 = gwave * QPW;            // first query id (global, 0..B*N2-1)
  int b = q0 >> 13;                // / N2 (QPW divides N2, no straddle)
  int n0 = q0 & (N2 - 1);

  const float* x2 = xyz2 + b * 3 * N2;
  float qx[QPW], qy[QPW], qz[QPW], qn[QPW];
  #pragma unroll
  for (int q = 0; q < QPW; ++q) {
    qx[q] = x2[n0 + q];
    qy[q] = x2[N2 + n0 + q];
    qz[q] = x2[2 * N2 + n0 + q];
    qn[q] = (qx[q] * qx[q] + qy[q] * qy[q]) + qz[q] * qz[q];
  }

  const float4* __restrict__ src = p1p + b * N1;

  bool ing[QPW];
  #pragma unroll
  for (int q = 0; q < QPW; ++q) ing[q] = (mygroup == q);
  const float NEG_INF = -INFINITY;

  float4 s = src[lane];   // chunk 0 (lane holds candidate `lane`)

  // ---- init: list = sorted candidates 0..15, per group, in parallel ----
  // broadcast candidate `sub` (0..15) to all 4 groups
  float bx = __shfl(s.x, sub);
  float by = __shfl(s.y, sub);
  float bz = __shfl(s.z, sub);
  float bw = __shfl(s.w, sub);
  float di[QPW];
  #pragma unroll
  for (int q = 0; q < QPW; ++q) {
    float dot = (bx * qx[q] + by * qy[q]) + bz * qz[q];
    di[q] = (qn[q] - 2.0f * dot) + bw;   // identical arithmetic to main loop
  }
  float dv = mygroup < 2 ? (mygroup == 0 ? di[0] : di[1])
                         : (mygroup == 2 ? di[2] : di[3]);
  int iv = sub;

  // bitonic sort-16 ascending on (dv, iv), lexicographic (tie -> smaller idx).
  // keep_min pattern per stage (k,j): ((sub&k)==0)==((sub&j)==0), 16-bit table.
#define CE_STAGE(J, KM)                                              \
  {                                                                  \
    float pd = lanexor_f<J>(dv);                                     \
    int pi = lanexor_i<J>(iv);                                       \
    bool ms = (dv < pd) || ((dv == pd) && (iv < pi));                \
    bool km = (((KM) >> sub) & 1) != 0;                              \
    bool tm = (ms == km);                                            \
    dv = tm ? dv : pd;                                               \
    iv = tm ? iv : pi;                                               \
  }
  CE_STAGE(1, 0x9999u)   // k=2  j=1
  CE_STAGE(2, 0xC3C3u)   // k=4  j=2
  CE_STAGE(1, 0xA5A5u)   // k=4  j=1
  CE_STAGE(4, 0xF00Fu)   // k=8  j=4
  CE_STAGE(2, 0xCC33u)   // k=8  j=2
  CE_STAGE(1, 0xAA55u)   // k=8  j=1
  CE_STAGE(8, 0x00FFu)   // k=16 j=8
  CE_STAGE(4, 0x0F0Fu)   // k=16 j=4
  CE_STAGE(2, 0x3333u)   // k=16 j=2
  CE_STAGE(1, 0x5555u)   // k=16 j=1
#undef CE_STAGE

  float val = dv;         // this lane's entry in its group's sorted top-16
  int vidx = iv;
  float kth[QPW];
  #pragma unroll
  for (int q = 0; q < QPW; ++q)
    kth[q] = __builtin_bit_cast(
        float, __builtin_amdgcn_readlane(__builtin_bit_cast(int, val),
                                         q * 16 + 15));

  // candidates 0..15 are already in the list; exclude them from chunk 0.
  unsigned long long excl = 0xFFFFull;

  #pragma unroll 1
  for (int c = 0; c < NCHUNK; ++c) {
    int nc = (c + 1 < NCHUNK) ? c + 1 : NCHUNK - 1;
    float4 nx = src[nc * 64 + lane];       // prefetch next chunk
    int base = c * 64;

    float d[QPW];
    #pragma unroll
    for (int q = 0; q < QPW; ++q) {
      float dot = (s.x * qx[q] + s.y * qy[q]) + s.z * qz[q];
      d[q] = (qn[q] - 2.0f * dot) + s.w;   // reference expansion order
    }

    unsigned long long b4[QPW], orb = 0;
    #pragma unroll
    for (int q = 0; q < QPW; ++q) {
      b4[q] = __ballot(d[q] < kth[q]) & ~excl;
      orb |= b4[q];
    }
    excl = 0;

    if (orb) {
      #pragma unroll
      for (int q = 0; q < QPW; ++q) {
        unsigned long long bal = b4[q];
        if (bal) {
          int dibits = __builtin_bit_cast(int, d[q]);
          do {
            int l = __ffsll(bal) - 1;
            bal &= bal - 1;
            float cd = __builtin_bit_cast(
                float, __builtin_amdgcn_readlane(dibits, l));
            int ci = base + l;
            float pv = dpp_up1_f(val, NEG_INF);
            int pi = dpp_up1_i(vidx);
            bool lt = cd < val;
            bool ltp = cd < pv;
            bool upd = ing[q] & lt;
            val = upd ? (ltp ? pv : cd) : val;
            vidx = upd ? (ltp ? pi : ci) : vidx;
          } while (bal);
          kth[q] = __builtin_bit_cast(
              float, __builtin_amdgcn_readlane(__builtin_bit_cast(int, val),
                                               q * 16 + 15));
        }
      }
    }
    s = nx;
  }

  // Gather the selected flows (each lane holds one of its group's 16) and
  // reduce within each 16-lane group (xor offsets 8,4,2,1 stay in-group).
  float4 f = f1p[b * N1 + vidx];
  float fx = f.x, fy = f.y, fz = f.z;
  #pragma unroll
  for (int o = 8; o > 0; o >>= 1) {
    fx += __shfl_xor(fx, o);
    fy += __shfl_xor(fy, o);
    fz += __shfl_xor(fz, o);
  }

  if (sub == 0) {
    int q = mygroup;
    float ox = qx[0], oy = qy[0], oz = qz[0];
    #pragma unroll
    for (int t = 1; t < QPW; ++t) {
      if (q == t) { ox = qx[t]; oy = qy[t]; oz = qz[t]; }
    }
    int n = n0 + q;
    float* op = out + b * 3 * N2;
    const float inv_k = 1.0f / KNN;
    op[n]          = ox - fx * inv_k;
    op[N2 + n]     = oy - fy * inv_k;
    op[2 * N2 + n] = oz - fz * inv_k;
  }
}

extern "C" void kernel_launch(void* const* d_in, const int* in_sizes, int n_in,
                              void* d_out, int out_size, void* d_ws, size_t ws_size,
                              hipStream_t stream) {
  const float* xyz1  = (const float*)d_in[0];
  const float* xyz2  = (const float*)d_in[1];
  const float* flow1 = (const float*)d_in[2];
  float* out = (float*)d_out;

  float4* p1p = (float4*)d_ws;
  float4* f1p = (float4*)((char*)d_ws + (size_t)NBATCH * N1 * sizeof(float4));

  {
    int total = NBATCH * N1;
    int threads = 256;
    int blocks = (total + threads - 1) / threads;
    pw3_prep_kernel<<<blocks, threads, 0, stream>>>(xyz1, flow1, p1p, f1p);
  }
  {
    int total_waves = (NBATCH * N2) / QPW;   // one wave per QPW queries
    int threads = 256;                       // 4 waves per block
    int blocks = total_waves * 64 / threads;
    pw3_knn_kernel<<<blocks, threads, 0, stream>>>(xyz2, p1p, f1p, out);
  }
}

// Round 5
// 101.267 us; speedup vs baseline: 1.0574x; 1.0574x over previous
//
#include <hip/hip_runtime.h>
#include <math.h>

#define N1 8192
#define N2 8192
#define NBATCH 2
#define KNN 16
#define QPW 2              // queries per wave (8192 waves = 8/SIMD, occupancy cap)
#define NCHUNK (N1 / 64)

// Pack p1 = xyz1 + flow1 as float4(x, y, z, |p1|^2), and f1 as float4(fx, fy, fz, 0).
__global__ __launch_bounds__(256) void pw3_prep_kernel(
    const float* __restrict__ xyz1,
    const float* __restrict__ flow1,
    float4* __restrict__ p1p,
    float4* __restrict__ f1p) {
  int i = blockIdx.x * blockDim.x + threadIdx.x;  // 0 .. B*N1-1
  if (i >= NBATCH * N1) return;
  int b = i >> 13;            // / N1
  int m = i & (N1 - 1);
  const float* x1 = xyz1 + b * 3 * N1;
  const float* f1 = flow1 + b * 3 * N1;
  float fx = f1[m], fy = f1[N1 + m], fz = f1[2 * N1 + m];
  float px = x1[m] + fx;
  float py = x1[N1 + m] + fy;
  float pz = x1[2 * N1 + m] + fz;
  float n1 = (px * px + py * py) + pz * pz;   // match reference (p1*p1).sum(-1)
  p1p[i] = make_float4(px, py, pz, n1);
  f1p[i] = make_float4(fx, fy, fz, 0.0f);
}

// DPP shift-up-by-1 within each 16-lane row (row_shr:1). Lanes 0/16/32/48
// receive `old` (we pass -INF so the "candidate < prev" test is false there).
__device__ __forceinline__ float dpp_up1_f(float x, float old_v) {
  int r = __builtin_amdgcn_update_dpp(
      __builtin_bit_cast(int, old_v), __builtin_bit_cast(int, x),
      0x111, 0xf, 0xf, false);
  return __builtin_bit_cast(float, r);
}
__device__ __forceinline__ int dpp_up1_i(int x) {
  return __builtin_amdgcn_update_dpp(0, x, 0x111, 0xf, 0xf, false);
}

// lane ^ J exchange: DPP quad_perm for J=1,2; ds_swizzle (xor mode) for J=4,8.
template <int J>
__device__ __forceinline__ int lanexor_i(int x) {
  if constexpr (J == 1)
    return __builtin_amdgcn_update_dpp(x, x, 0xB1, 0xf, 0xf, false);  // [1,0,3,2]
  else if constexpr (J == 2)
    return __builtin_amdgcn_update_dpp(x, x, 0x4E, 0xf, 0xf, false);  // [2,3,0,1]
  else
    return __builtin_amdgcn_ds_swizzle(x, (J << 10) | 0x1F);
}
template <int J>
__device__ __forceinline__ float lanexor_f(float x) {
  return __builtin_bit_cast(float, lanexor_i<J>(__builtin_bit_cast(int, x)));
}

// One wave handles QPW=2 queries. Groups 0,1 (16 lanes each) own one query's
// sorted top-16 (dist,idx), one entry per lane, ascending (sub 15 = kth).
// Groups 2,3 mirror group 1's list harmlessly (never update, never output).
__global__ __launch_bounds__(256) void pw3_knn_kernel(
    const float* __restrict__ xyz2,
    const float4* __restrict__ p1p,
    const float4* __restrict__ f1p,
    float* __restrict__ out) {
  int lane = threadIdx.x & 63;
  int sub = lane & 15;
  int mygroup = lane >> 4;
  int gwave = (int)((blockIdx.x * blockDim.x + threadIdx.x) >> 6);
  int q0 = gwave * QPW;            // first query id (global, 0..B*N2-1)
  int b = q0 >> 13;                // / N2 (QPW divides N2, no straddle)
  int n0 = q0 & (N2 - 1);

  const float* x2 = xyz2 + b * 3 * N2;
  float qx[QPW], qy[QPW], qz[QPW], qn[QPW];
  #pragma unroll
  for (int q = 0; q < QPW; ++q) {
    qx[q] = x2[n0 + q];
    qy[q] = x2[N2 + n0 + q];
    qz[q] = x2[2 * N2 + n0 + q];
    qn[q] = (qx[q] * qx[q] + qy[q] * qy[q]) + qz[q] * qz[q];
  }

  const float4* __restrict__ src = p1p + b * N1;

  bool ing[QPW];
  #pragma unroll
  for (int q = 0; q < QPW; ++q) ing[q] = (mygroup == q);
  const float NEG_INF = -INFINITY;

  float4 s0 = src[lane];        // chunk 0
  float4 s1 = src[64 + lane];   // chunk 1 (depth-2 prefetch pipeline)

  // ---- init: list = sorted candidates 0..15, per group, in parallel ----
  float bx = __shfl(s0.x, sub);
  float by = __shfl(s0.y, sub);
  float bz = __shfl(s0.z, sub);
  float bw = __shfl(s0.w, sub);
  float di[QPW];
  #pragma unroll
  for (int q = 0; q < QPW; ++q) {
    float dot = (bx * qx[q] + by * qy[q]) + bz * qz[q];
    di[q] = (qn[q] - 2.0f * dot) + bw;   // identical arithmetic to main loop
  }
  float dv = (mygroup == 0) ? di[0] : di[1];   // groups 2,3 mirror group 1
  int iv = sub;

  // bitonic sort-16 ascending on (dv, iv), lexicographic (tie -> smaller idx).
#define CE_STAGE(J, KM)                                              \
  {                                                                  \
    float pd = lanexor_f<J>(dv);                                     \
    int pi = lanexor_i<J>(iv);                                       \
    bool ms = (dv < pd) || ((dv == pd) && (iv < pi));                \
    bool km = (((KM) >> sub) & 1) != 0;                              \
    bool tm = (ms == km);                                            \
    dv = tm ? dv : pd;                                               \
    iv = tm ? iv : pi;                                               \
  }
  CE_STAGE(1, 0x9999u)   // k=2  j=1
  CE_STAGE(2, 0xC3C3u)   // k=4  j=2
  CE_STAGE(1, 0xA5A5u)   // k=4  j=1
  CE_STAGE(4, 0xF00Fu)   // k=8  j=4
  CE_STAGE(2, 0xCC33u)   // k=8  j=2
  CE_STAGE(1, 0xAA55u)   // k=8  j=1
  CE_STAGE(8, 0x00FFu)   // k=16 j=8
  CE_STAGE(4, 0x0F0Fu)   // k=16 j=4
  CE_STAGE(2, 0x3333u)   // k=16 j=2
  CE_STAGE(1, 0x5555u)   // k=16 j=1
#undef CE_STAGE

  float val = dv;         // this lane's entry in its group's sorted top-16
  int vidx = iv;
  float kth[QPW];
  #pragma unroll
  for (int q = 0; q < QPW; ++q)
    kth[q] = __builtin_bit_cast(
        float, __builtin_amdgcn_readlane(__builtin_bit_cast(int, val),
                                         q * 16 + 15));

  // candidates 0..15 are already in the list; exclude them from chunk 0.
  unsigned long long excl = 0xFFFFull;

  #pragma unroll 1
  for (int c = 0; c < NCHUNK; ++c) {
    int nc = (c + 2 < NCHUNK) ? c + 2 : NCHUNK - 1;
    float4 nx = src[nc * 64 + lane];       // prefetch 2 chunks ahead
    int base = c * 64;

    float d[QPW];
    #pragma unroll
    for (int q = 0; q < QPW; ++q) {
      float dot = (s0.x * qx[q] + s0.y * qy[q]) + s0.z * qz[q];
      d[q] = (qn[q] - 2.0f * dot) + s0.w;  // reference expansion order
    }

    unsigned long long b4[QPW], orb = 0;
    #pragma unroll
    for (int q = 0; q < QPW; ++q) {
      b4[q] = __ballot(d[q] < kth[q]) & ~excl;
      orb |= b4[q];
    }
    excl = 0;

    if (orb) {
      #pragma unroll
      for (int q = 0; q < QPW; ++q) {
        unsigned long long bal = b4[q];
        if (bal) {
          int dibits = __builtin_bit_cast(int, d[q]);
          do {
            int l = __ffsll(bal) - 1;
            bal &= bal - 1;
            float cd = __builtin_bit_cast(
                float, __builtin_amdgcn_readlane(dibits, l));
            int ci = base + l;
            float pv = dpp_up1_f(val, NEG_INF);
            int pi = dpp_up1_i(vidx);
            bool lt = cd < val;
            bool ltp = cd < pv;
            bool upd = ing[q] & lt;
            val = upd ? (ltp ? pv : cd) : val;
            vidx = upd ? (ltp ? pi : ci) : vidx;
          } while (bal);
          kth[q] = __builtin_bit_cast(
              float, __builtin_amdgcn_readlane(__builtin_bit_cast(int, val),
                                               q * 16 + 15));
        }
      }
    }
    s0 = s1;
    s1 = nx;
  }

  // Gather the selected flows (each lane holds one of its group's 16) and
  // reduce within each 16-lane group (xor offsets 8,4,2,1 stay in-group).
  float4 f = f1p[b * N1 + vidx];
  float fx = f.x, fy = f.y, fz = f.z;
  #pragma unroll
  for (int o = 8; o > 0; o >>= 1) {
    fx += __shfl_xor(fx, o);
    fy += __shfl_xor(fy, o);
    fz += __shfl_xor(fz, o);
  }

  if (sub == 0 && mygroup < QPW) {
    int q = mygroup;
    float ox = qx[0], oy = qy[0], oz = qz[0];
    #pragma unroll
    for (int t = 1; t < QPW; ++t) {
      if (q == t) { ox = qx[t]; oy = qy[t]; oz = qz[t]; }
    }
    int n = n0 + q;
    float* op = out + b * 3 * N2;
    const float inv_k = 1.0f / KNN;
    op[n]          = ox - fx * inv_k;
    op[N2 + n]     = oy - fy * inv_k;
    op[2 * N2 + n] = oz - fz * inv_k;
  }
}

extern "C" void kernel_launch(void* const* d_in, const int* in_sizes, int n_in,
                              void* d_out, int out_size, void* d_ws, size_t ws_size,
                              hipStream_t stream) {
  const float* xyz1  = (const float*)d_in[0];
  const float* xyz2  = (const float*)d_in[1];
  const float* flow1 = (const float*)d_in[2];
  float* out = (float*)d_out;

  float4* p1p = (float4*)d_ws;
  float4* f1p = (float4*)((char*)d_ws + (size_t)NBATCH * N1 * sizeof(float4));

  {
    int total = NBATCH * N1;
    int threads = 256;
    int blocks = (total + threads - 1) / threads;
    pw3_prep_kernel<<<blocks, threads, 0, stream>>>(xyz1, flow1, p1p, f1p);
  }
  {
    int total_waves = (NBATCH * N2) / QPW;   // one wave per QPW queries
    int threads = 256;                       // 4 waves per block
    int blocks = total_waves * 64 / threads;
    pw3_knn_kernel<<<blocks, threads, 0, stream>>>(xyz2, p1p, f1p, out);
  }
}